// Round 1
// baseline (50.379 us; speedup 1.0000x reference)
//
#include <hip/hip_runtime.h>

#define EPS 1e-5f

// ws layout: bytes [0,64): double acc[8] = {sum[4], sumsq[4]}; bytes [1024, 1024+bsz*16): float z[bsz*4]

__global__ __launch_bounds__(256) void qnat_stage1(const float* __restrict__ x,
                                                   float* __restrict__ z_out,
                                                   double* __restrict__ acc,
                                                   int bsz) {
    const int tid = blockIdx.x * blockDim.x + threadIdx.x;
    const int img = tid >> 2;   // image index
    const int p   = tid & 3;    // which theta (qubit)
    const bool valid = (img < bsz);

    float c = 0.0f;
    if (valid) {
        const float* row = x + (size_t)img * 784 + (size_t)p * 6 * 28;
        float s = 0.0f;
        #pragma unroll
        for (int r = 0; r < 6; ++r) {
            const float4 v4 = *reinterpret_cast<const float4*>(row + r * 28);
            const float2 v2 = *reinterpret_cast<const float2*>(row + r * 28 + 4);
            s += ((v4.x + v4.y) + (v4.z + v4.w)) + (v2.x + v2.y);
        }
        const float theta = s * (1.0f / 36.0f);
        c = cosf(theta);
    }

    // gather c0..c3 within the lane-quad (quad is img-uniform, so no divergence issue)
    const int lane = threadIdx.x & 63;
    const int base = lane & ~3;
    const float c0 = __shfl(c, base + 0, 64);
    const float c1 = __shfl(c, base + 1, 64);
    const float c2 = __shfl(c, base + 2, 64);
    const float c3 = __shfl(c, base + 3, 64);

    float zv;
    const float t01 = c0 * c1;
    if      (p == 0) zv = c1 * c2 * c3;
    else if (p == 1) zv = t01;
    else if (p == 2) zv = t01 * c2;
    else             zv = t01 * c2 * c3;
    if (!valid) zv = 0.0f;

    if (valid) z_out[tid] = zv;   // coalesced: consecutive lanes -> consecutive addrs

    // block reduction of sum/sumsq per channel p (lanes with same lane%4)
    float s1 = zv, s2 = zv * zv;
    #pragma unroll
    for (int off = 32; off >= 4; off >>= 1) {
        s1 += __shfl_xor(s1, off, 64);
        s2 += __shfl_xor(s2, off, 64);
    }
    __shared__ float ls1[4][4], ls2[4][4];  // [wave][channel]
    const int wv = threadIdx.x >> 6;
    if (lane < 4) { ls1[wv][lane] = s1; ls2[wv][lane] = s2; }
    __syncthreads();
    if (threadIdx.x < 4) {
        const int k = threadIdx.x;
        const float t1 = (ls1[0][k] + ls1[1][k]) + (ls1[2][k] + ls1[3][k]);
        const float t2 = (ls2[0][k] + ls2[1][k]) + (ls2[2][k] + ls2[3][k]);
        atomicAdd(&acc[k],     (double)t1);
        atomicAdd(&acc[4 + k], (double)t2);
    }
}

__global__ __launch_bounds__(256) void qnat_stage2(const float* __restrict__ z,
                                                   const double* __restrict__ acc,
                                                   const float* __restrict__ gamma,
                                                   const float* __restrict__ beta,
                                                   float* __restrict__ out,
                                                   int bsz) {
    const double invB = 1.0 / (double)bsz;
    float mean[4], scale[4], bet[4];
    #pragma unroll
    for (int k = 0; k < 4; ++k) {
        const double m = acc[k] * invB;
        const double v = acc[4 + k] * invB - m * m;
        mean[k]  = (float)m;
        scale[k] = gamma[k] * rsqrtf((float)v + EPS);
        bet[k]   = beta[k];
    }
    const int t = blockIdx.x * blockDim.x + threadIdx.x;
    if (t < bsz) {
        const float4 zv = reinterpret_cast<const float4*>(z)[t];
        float4 o;
        o.x = (zv.x - mean[0]) * scale[0] + bet[0];
        o.y = (zv.y - mean[1]) * scale[1] + bet[1];
        o.z = (zv.z - mean[2]) * scale[2] + bet[2];
        o.w = (zv.w - mean[3]) * scale[3] + bet[3];
        reinterpret_cast<float4*>(out)[t] = o;
    }
}

extern "C" void kernel_launch(void* const* d_in, const int* in_sizes, int n_in,
                              void* d_out, int out_size, void* d_ws, size_t ws_size,
                              hipStream_t stream) {
    const float* x     = (const float*)d_in[0];
    const float* gamma = (const float*)d_in[1];
    const float* beta  = (const float*)d_in[2];
    float* out = (float*)d_out;

    const int bsz = in_sizes[0] / 784;

    double* acc = (double*)d_ws;
    float*  z   = (float*)((char*)d_ws + 1024);

    hipMemsetAsync(d_ws, 0, 64, stream);

    const int threads1 = bsz * 4;
    qnat_stage1<<<(threads1 + 255) / 256, 256, 0, stream>>>(x, z, acc, bsz);
    qnat_stage2<<<(bsz + 255) / 256, 256, 0, stream>>>(z, acc, gamma, beta, out, bsz);
}